// Round 5
// baseline (351.470 us; speedup 1.0000x reference)
//
#include <hip/hip_runtime.h>
#include <hip/hip_bf16.h>
#include <cstdint>

#define B_   2
#define NQ_  10000
#define C_   256
#define NH_  8
#define DH_  32
#define DFF_ 1024
#define S_   19560
#define MQ_P 20096   // 157*128
#define MV_P 39168   // 306*128

typedef __attribute__((ext_vector_type(8))) short short8;
typedef __attribute__((ext_vector_type(4))) float f32x4;

__device__ __forceinline__ void gload16(const void* g, void* l) {
  __builtin_amdgcn_global_load_lds(
      (const __attribute__((address_space(1))) unsigned int*)g,
      (__attribute__((address_space(3))) unsigned int*)l, 16, 0, 0);
}

__device__ __forceinline__ float bflo(unsigned u) {
  union { unsigned u; float f; } c; c.u = u << 16; return c.f;
}
__device__ __forceinline__ float bfhi(unsigned u) {
  union { unsigned u; float f; } c; c.u = u & 0xffff0000u; return c.f;
}

// ------------------------------------------------------------- weight conv+T
// Wt[n][k] = bf16(W[k][n]); layout: Wv | Woff | Wa | Wo | W1 | W2
__global__ __launch_bounds__(256) void conv_weights(
    const float* __restrict__ Wv, const float* __restrict__ Woff,
    const float* __restrict__ Wa, const float* __restrict__ Wo,
    const float* __restrict__ W1, const float* __restrict__ W2,
    __hip_bfloat16* __restrict__ wbase) {
  int idx = blockIdx.x * 256 + threadIdx.x;
  const float* W; __hip_bfloat16* Wt; int K, N, local;
  if (idx < 65536)        { W = Wv;   Wt = wbase + 0;      K = 256;  N = 256;  local = idx; }
  else if (idx < 131072)  { W = Woff; Wt = wbase + 65536;  K = 256;  N = 256;  local = idx - 65536; }
  else if (idx < 163840)  { W = Wa;   Wt = wbase + 131072; K = 256;  N = 128;  local = idx - 131072; }
  else if (idx < 229376)  { W = Wo;   Wt = wbase + 163840; K = 256;  N = 256;  local = idx - 163840; }
  else if (idx < 491520)  { W = W1;   Wt = wbase + 229376; K = 256;  N = 1024; local = idx - 229376; }
  else if (idx < 753664)  { W = W2;   Wt = wbase + 491520; K = 1024; N = 256;  local = idx - 491520; }
  else return;
  int k = local % K, n = local / K;
  Wt[(long)n * K + k] = __float2bfloat16(W[(long)k * N + n]);
}

// ------------------------------------------------------------- input prep
__global__ __launch_bounds__(256) void prep_inputs(
    const float* __restrict__ src, const float* __restrict__ qf,
    const float* __restrict__ qp, __hip_bfloat16* __restrict__ src_bf,
    __hip_bfloat16* __restrict__ q_bf) {
  long idx = (long)blockIdx.x * 256 + threadIdx.x;
  union { __hip_bfloat16 h[8]; uint4 u; } o;
  if (idx < (long)MV_P * 32) {
    int row = idx >> 5, c8 = (idx & 31) * 8;
    if (row < B_ * S_) {
      const float4 a = *reinterpret_cast<const float4*>(src + (long)row * 256 + c8);
      const float4 b = *reinterpret_cast<const float4*>(src + (long)row * 256 + c8 + 4);
      o.h[0] = __float2bfloat16(a.x); o.h[1] = __float2bfloat16(a.y);
      o.h[2] = __float2bfloat16(a.z); o.h[3] = __float2bfloat16(a.w);
      o.h[4] = __float2bfloat16(b.x); o.h[5] = __float2bfloat16(b.y);
      o.h[6] = __float2bfloat16(b.z); o.h[7] = __float2bfloat16(b.w);
    } else o.u = make_uint4(0, 0, 0, 0);
    *reinterpret_cast<uint4*>(src_bf + (long)row * 256 + c8) = o.u;
  } else {
    idx -= (long)MV_P * 32;
    int row = idx >> 5, c8 = (idx & 31) * 8;
    if (row < B_ * NQ_) {
      const float4 a0 = *reinterpret_cast<const float4*>(qf + (long)row * 256 + c8);
      const float4 a1 = *reinterpret_cast<const float4*>(qf + (long)row * 256 + c8 + 4);
      const float4 b0 = *reinterpret_cast<const float4*>(qp + (long)row * 256 + c8);
      const float4 b1 = *reinterpret_cast<const float4*>(qp + (long)row * 256 + c8 + 4);
      o.h[0] = __float2bfloat16(a0.x + b0.x); o.h[1] = __float2bfloat16(a0.y + b0.y);
      o.h[2] = __float2bfloat16(a0.z + b0.z); o.h[3] = __float2bfloat16(a0.w + b0.w);
      o.h[4] = __float2bfloat16(a1.x + b1.x); o.h[5] = __float2bfloat16(a1.y + b1.y);
      o.h[6] = __float2bfloat16(a1.z + b1.z); o.h[7] = __float2bfloat16(a1.w + b1.w);
    } else o.u = make_uint4(0, 0, 0, 0);
    *reinterpret_cast<uint4*>(q_bf + (long)row * 256 + c8) = o.u;
  }
}

// ------------------------------------------------------------- MFMA GEMM
template <int MODE>
__global__ __launch_bounds__(256) void gemm_bf16(
    const __hip_bfloat16* __restrict__ A, const __hip_bfloat16* __restrict__ Bt,
    const float* __restrict__ bias, const float* __restrict__ bias2, int bsplit,
    void* __restrict__ Cp, int M, int N, int K, int Mreal) {
  __shared__ short smA[64 * 64];    // 8KB
  __shared__ short smB[128 * 64];   // 16KB
  const int tid = threadIdx.x;
  const int lane = tid & 63;
  const int w = tid >> 6;
  const int wr = w >> 1, wc = w & 1;
  const long bm = (long)blockIdx.x * 64;
  const long bn = (long)blockIdx.y * 128;

  f32x4 acc[2][4];
#pragma unroll
  for (int i = 0; i < 2; ++i)
#pragma unroll
    for (int j = 0; j < 4; ++j) acc[i][j] = (f32x4)(0.f);

  const int srow = tid >> 3;                 // 0..31
  const int su = (tid & 7) ^ (srow & 7);     // pre-swizzled k-unit
  const __hip_bfloat16* Ag = A + (bm + srow) * (long)K + su * 8;
  const __hip_bfloat16* Bg = Bt + (bn + srow) * (long)K + su * 8;
  char* lA = (char*)smA + tid * 16;
  char* lB = (char*)smB + tid * 16;

  for (int k0 = 0; k0 < K; k0 += 64) {
    gload16(Ag,           lA);
    gload16(Ag + 32L * K, lA + 4096);
    gload16(Bg,           lB);
    gload16(Bg + 32L * K, lB + 4096);
    gload16(Bg + 64L * K, lB + 8192);
    gload16(Bg + 96L * K, lB + 12288);
    Ag += 64; Bg += 64;
    __syncthreads();
#pragma unroll
    for (int ks = 0; ks < 2; ++ks) {
      const int u = ks * 4 + (lane >> 4);
      short8 af[2], bf[4];
#pragma unroll
      for (int mi = 0; mi < 2; ++mi) {
        const int r = wr * 32 + (lane & 15) + mi * 16;
        af[mi] = *reinterpret_cast<const short8*>(
            (char*)smA + r * 128 + ((u ^ (r & 7)) * 16));
      }
#pragma unroll
      for (int ni = 0; ni < 4; ++ni) {
        const int r = wc * 64 + (lane & 15) + ni * 16;
        bf[ni] = *reinterpret_cast<const short8*>(
            (char*)smB + r * 128 + ((u ^ (r & 7)) * 16));
      }
#pragma unroll
      for (int mi = 0; mi < 2; ++mi)
#pragma unroll
        for (int ni = 0; ni < 4; ++ni)
          acc[mi][ni] = __builtin_amdgcn_mfma_f32_16x16x32_bf16(af[mi], bf[ni], acc[mi][ni], 0, 0, 0);
    }
    __syncthreads();
  }

  const int crow0 = wr * 32 + ((lane >> 4) << 2);
  const int ccol0 = wc * 64 + (lane & 15);
#pragma unroll
  for (int mi = 0; mi < 2; ++mi) {
#pragma unroll
    for (int ni = 0; ni < 4; ++ni) {
      const int col = bn + ccol0 + ni * 16;
      const float bs = (col < bsplit) ? bias[col] : bias2[col - bsplit];
#pragma unroll
      for (int r = 0; r < 4; ++r) {
        const long row = bm + crow0 + mi * 16 + r;
        float v = acc[mi][ni][r] + bs;
        if (MODE == 0) {
          ((float*)Cp)[row * N + col] = v;
        } else if (MODE == 2) {
          ((__hip_bfloat16*)Cp)[row * N + col] = __float2bfloat16(fmaxf(v, 0.f));
        } else if (MODE == 4) {
          ((__hip_bfloat16*)Cp)[row * N + col] = __float2bfloat16(v);
        } else { // MODE 3
          if (row < Mreal) {
            const int b = (row >= S_) ? 1 : 0;
            const long s = row - (long)b * S_;
            const int h = col >> 5, dh = col & 31;
            ((__hip_bfloat16*)Cp)[(((long)(b * 8 + h)) * S_ + s) * 32 + dh] = __float2bfloat16(v);
          }
        }
      }
    }
  }
}

// ------------------------------------------------------------- ms_deform
// value bf16 [B][NH][S][32]; oa bf16 [bq][384]: 0..255 offsets (h,l,p,2),
// 256..383 logits (h,l*p). out bf16 [MQ_P][256] rows<20000.
// One wave per query: lane = dq(1b) | l(2b) | h(3b).
// Softmax distributed: each lane owns 4 logits; max/sum via shfl_xor(2,4).
__global__ __launch_bounds__(256, 5) void msdeform_kernel(
    const __hip_bfloat16* __restrict__ value, const __hip_bfloat16* __restrict__ oa,
    const float* __restrict__ q_ref, const float* __restrict__ vr,
    __hip_bfloat16* __restrict__ out) {
  const int t = blockIdx.x * 256 + threadIdx.x;
  const int dq = t & 1;
  const int l = (t >> 1) & 3;
  const int h = (t >> 3) & 7;
  const int bq = __builtin_amdgcn_readfirstlane(t >> 6);   // wave-uniform
  const int b = (bq >= NQ_) ? 1 : 0;

  const int W  = (l == 0) ? 160 : (l == 1) ? 80 : (l == 2) ? 40 : 20;
  const int H  = (l == 0) ? 92  : (l == 1) ? 46 : (l == 2) ? 23 : 12;
  const int S0 = (l == 0) ? 0 : (l == 1) ? 14720 : (l == 2) ? 18400 : 19320;

  const __hip_bfloat16* oabase = oa + (long)bq * 384;      // SGPR base
  // this lane's 4 logits; softmax reduced across the 4 l-lanes of head h
  const uint2 mu = *reinterpret_cast<const uint2*>(oabase + 256 + h * 16 + l * 4);
  const float l0 = bflo(mu.x), l1 = bfhi(mu.x), l2 = bflo(mu.y), l3 = bfhi(mu.y);
  float mx = fmaxf(fmaxf(l0, l1), fmaxf(l2, l3));
  mx = fmaxf(mx, __shfl_xor(mx, 2, 64));
  mx = fmaxf(mx, __shfl_xor(mx, 4, 64));
  const float e0 = __expf(l0 - mx), e1 = __expf(l1 - mx);
  const float e2 = __expf(l2 - mx), e3 = __expf(l3 - mx);
  float sum = e0 + e1 + e2 + e3;
  sum += __shfl_xor(sum, 2, 64);
  sum += __shfl_xor(sum, 4, 64);
  const float inv = 1.f / sum;
  const float w0 = e0 * inv, w1 = e1 * inv, w2 = e2 * inv, w3 = e3 * inv;

  const uint4 ou = *reinterpret_cast<const uint4*>(oabase + h * 32 + l * 8);

  const float rx = q_ref[(long)bq * 2 + 0];                // scalar loads
  const float ry = q_ref[(long)bq * 2 + 1];
  const float2 vv = *reinterpret_cast<const float2*>(vr + (b * 4 + l) * 2);
  const float refxW = rx * vv.x * W - 0.5f;
  const float refyH = ry * vv.y * H - 0.5f;
  const __hip_bfloat16* vb = value + ((long)(b * 8 + h) * S_ + S0) * 32 + dq * 16;

  float acc[16] = {};
#define SAMPLE(OX, OY, AW)                                                     \
  {                                                                            \
    const float x = refxW + (OX);                                              \
    const float y = refyH + (OY);                                              \
    const float x0f = floorf(x), y0f = floorf(y);                              \
    const float lx = x - x0f, ly = y - y0f;                                    \
    const int x0 = (int)x0f, y0 = (int)y0f;                                    \
    const int x1 = x0 + 1, y1 = y0 + 1;                                        \
    const float wx0 = ((unsigned)x0 < (unsigned)W) ? (1.f - lx) : 0.f;         \
    const float wx1 = ((unsigned)x1 < (unsigned)W) ? lx : 0.f;                 \
    const float wy0 = ((unsigned)y0 < (unsigned)H) ? (1.f - ly) : 0.f;         \
    const float wy1 = ((unsigned)y1 < (unsigned)H) ? ly : 0.f;                 \
    const int x0c = min(max(x0, 0), W - 1);                                    \
    const int x1c = min(max(x1, 0), W - 1);                                    \
    const int y0c = min(max(y0, 0), H - 1);                                    \
    const int y1c = min(max(y1, 0), H - 1);                                    \
    const float w00 = (AW) * wx0 * wy0, w10 = (AW) * wx1 * wy0;                \
    const float w01 = (AW) * wx0 * wy1, w11 = (AW) * wx1 * wy1;                \
    const __hip_bfloat16* p00 = vb + (long)(y0c * W + x0c) * 32;               \
    const __hip_bfloat16* p10 = vb + (long)(y0c * W + x1c) * 32;               \
    const __hip_bfloat16* p01 = vb + (long)(y1c * W + x0c) * 32;               \
    const __hip_bfloat16* p11 = vb + (long)(y1c * W + x1c) * 32;               \
    const uint4 a0 = *reinterpret_cast<const uint4*>(p00);                     \
    const uint4 a1 = *reinterpret_cast<const uint4*>(p00 + 8);                 \
    const uint4 b0 = *reinterpret_cast<const uint4*>(p10);                     \
    const uint4 b1 = *reinterpret_cast<const uint4*>(p10 + 8);                 \
    const uint4 c0 = *reinterpret_cast<const uint4*>(p01);                     \
    const uint4 c1 = *reinterpret_cast<const uint4*>(p01 + 8);                 \
    const uint4 d0 = *reinterpret_cast<const uint4*>(p11);                     \
    const uint4 d1 = *reinterpret_cast<const uint4*>(p11 + 8);                 \
    acc[0] += w00 * bflo(a0.x) + w10 * bflo(b0.x) + w01 * bflo(c0.x) + w11 * bflo(d0.x); \
    acc[1] += w00 * bfhi(a0.x) + w10 * bfhi(b0.x) + w01 * bfhi(c0.x) + w11 * bfhi(d0.x); \
    acc[2] += w00 * bflo(a0.y) + w10 * bflo(b0.y) + w01 * bflo(c0.y) + w11 * bflo(d0.y); \
    acc[3] += w00 * bfhi(a0.y) + w10 * bfhi(b0.y) + w01 * bfhi(c0.y) + w11 * bfhi(d0.y); \
    acc[4] += w00 * bflo(a0.z) + w10 * bflo(b0.z) + w01 * bflo(c0.z) + w11 * bflo(d0.z); \
    acc[5] += w00 * bfhi(a0.z) + w10 * bfhi(b0.z) + w01 * bfhi(c0.z) + w11 * bfhi(d0.z); \
    acc[6] += w00 * bflo(a0.w) + w10 * bflo(b0.w) + w01 * bflo(c0.w) + w11 * bflo(d0.w); \
    acc[7] += w00 * bfhi(a0.w) + w10 * bfhi(b0.w) + w01 * bfhi(c0.w) + w11 * bfhi(d0.w); \
    acc[8]  += w00 * bflo(a1.x) + w10 * bflo(b1.x) + w01 * bflo(c1.x) + w11 * bflo(d1.x); \
    acc[9]  += w00 * bfhi(a1.x) + w10 * bfhi(b1.x) + w01 * bfhi(c1.x) + w11 * bfhi(d1.x); \
    acc[10] += w00 * bflo(a1.y) + w10 * bflo(b1.y) + w01 * bflo(c1.y) + w11 * bflo(d1.y); \
    acc[11] += w00 * bfhi(a1.y) + w10 * bfhi(b1.y) + w01 * bfhi(c1.y) + w11 * bfhi(d1.y); \
    acc[12] += w00 * bflo(a1.z) + w10 * bflo(b1.z) + w01 * bflo(c1.z) + w11 * bflo(d1.z); \
    acc[13] += w00 * bfhi(a1.z) + w10 * bfhi(b1.z) + w01 * bfhi(c1.z) + w11 * bfhi(d1.z); \
    acc[14] += w00 * bflo(a1.w) + w10 * bflo(b1.w) + w01 * bflo(c1.w) + w11 * bflo(d1.w); \
    acc[15] += w00 * bfhi(a1.w) + w10 * bfhi(b1.w) + w01 * bfhi(c1.w) + w11 * bfhi(d1.w); \
  }
  SAMPLE(bflo(ou.x), bfhi(ou.x), w0)
  SAMPLE(bflo(ou.y), bfhi(ou.y), w1)
  SAMPLE(bflo(ou.z), bfhi(ou.z), w2)
  SAMPLE(bflo(ou.w), bfhi(ou.w), w3)
#undef SAMPLE

#pragma unroll
  for (int j = 0; j < 16; ++j) acc[j] += __shfl_xor(acc[j], 2, 64);
#pragma unroll
  for (int j = 0; j < 16; ++j) acc[j] += __shfl_xor(acc[j], 4, 64);

  if (l == 0) {
    union { __hip_bfloat16 hh[8]; uint4 u; } o0, o1;
#pragma unroll
    for (int j = 0; j < 8; ++j) {
      o0.hh[j] = __float2bfloat16(acc[j]);
      o1.hh[j] = __float2bfloat16(acc[j + 8]);
    }
    __hip_bfloat16* op = out + (long)bq * 256 + h * 32 + dq * 16;
    *reinterpret_cast<uint4*>(op) = o0.u;
    *reinterpret_cast<uint4*>(op + 8) = o1.u;
  }
}

// ------------------------------------------------------------- residual+LN
__global__ __launch_bounds__(256) void add_ln_kernel(
    const float* __restrict__ res, const float* __restrict__ xin,
    const float* __restrict__ gamma, const float* __restrict__ beta,
    float* __restrict__ out, __hip_bfloat16* __restrict__ out_bf, int nrows) {
  int row = blockIdx.x * 4 + (threadIdx.x >> 6);
  int lane = threadIdx.x & 63;
  if (row >= nrows) return;
  const float4 r4 = *reinterpret_cast<const float4*>(res + (long)row * 256 + lane * 4);
  const float4 x4 = *reinterpret_cast<const float4*>(xin + (long)row * 256 + lane * 4);
  float tv[4] = {r4.x + x4.x, r4.y + x4.y, r4.z + x4.z, r4.w + x4.w};
  float s = tv[0] + tv[1] + tv[2] + tv[3];
#pragma unroll
  for (int o = 32; o > 0; o >>= 1) s += __shfl_xor(s, o, 64);
  float mean = s * (1.f / 256.f);
  float vs = 0.f;
#pragma unroll
  for (int j = 0; j < 4; ++j) { float dd = tv[j] - mean; vs += dd * dd; }
#pragma unroll
  for (int o = 32; o > 0; o >>= 1) vs += __shfl_xor(vs, o, 64);
  float inv = rsqrtf(vs * (1.f / 256.f) + 1e-5f);
  const float4 g = *reinterpret_cast<const float4*>(gamma + lane * 4);
  const float4 be = *reinterpret_cast<const float4*>(beta + lane * 4);
  float4 o4;
  o4.x = (tv[0] - mean) * inv * g.x + be.x;
  o4.y = (tv[1] - mean) * inv * g.y + be.y;
  o4.z = (tv[2] - mean) * inv * g.z + be.z;
  o4.w = (tv[3] - mean) * inv * g.w + be.w;
  *reinterpret_cast<float4*>(out + (long)row * 256 + lane * 4) = o4;
  if (out_bf) {
    union { __hip_bfloat16 h[4]; uint2 u; } p;
    p.h[0] = __float2bfloat16(o4.x); p.h[1] = __float2bfloat16(o4.y);
    p.h[2] = __float2bfloat16(o4.z); p.h[3] = __float2bfloat16(o4.w);
    *reinterpret_cast<uint2*>(out_bf + (long)row * 256 + lane * 4) = p.u;
  }
}

// ------------------------------------------------------------- launch
extern "C" void kernel_launch(void* const* d_in, const int* in_sizes, int n_in,
                              void* d_out, int out_size, void* d_ws, size_t ws_size,
                              hipStream_t stream) {
  const float* src    = (const float*)d_in[0];
  const float* q_feat = (const float*)d_in[1];
  const float* q_pos  = (const float*)d_in[2];
  const float* q_ref  = (const float*)d_in[3];
  const float* vr     = (const float*)d_in[4];
  const float* Wv     = (const float*)d_in[5];
  const float* bv     = (const float*)d_in[6];
  const float* Woff   = (const float*)d_in[7];
  const float* boff   = (const float*)d_in[8];
  const float* Wa     = (const float*)d_in[9];
  const float* ba     = (const float*)d_in[10];
  const float* Wo     = (const float*)d_in[11];
  const float* bo     = (const float*)d_in[12];
  const float* g1     = (const float*)d_in[13];
  const float* be1    = (const float*)d_in[14];
  const float* W1     = (const float*)d_in[15];
  const float* bf1    = (const float*)d_in[16];
  const float* W2     = (const float*)d_in[17];
  const float* bf2    = (const float*)d_in[18];
  const float* g2     = (const float*)d_in[19];
  const float* be2    = (const float*)d_in[20];

  char* ws = (char*)d_ws;
  __hip_bfloat16* src_bf = (__hip_bfloat16*)(ws + 0);          // 20,054,016
  float*          a_f    = (float*)(ws + 0);                   // reuse (20,578,304)
  __hip_bfloat16* q_bf   = (__hip_bfloat16*)(ws + 20578304);   // 10,289,152
  __hip_bfloat16* val_bf = (__hip_bfloat16*)(ws + 30867456);   // 20,029,440
  __hip_bfloat16* oa_bf  = (__hip_bfloat16*)(ws + 50896896);   // 15,433,728
  __hip_bfloat16* h1_bf  = (__hip_bfloat16*)(ws + 20578304);   // reuse q/val/oa
  __hip_bfloat16* ms_bf  = (__hip_bfloat16*)(ws + 81764352);   // 10,289,152
  float*          f2_f   = (float*)(ws + 71475200);            // dead region reuse
  float*          x_f    = (float*)(ws + 92053504);            // 20,578,304
  __hip_bfloat16* x_bf   = (__hip_bfloat16*)(ws + 112631808);  // 10,289,152
  __hip_bfloat16* wts    = (__hip_bfloat16*)(ws + 122920960);  // 1,507,328
  float* outp = (float*)d_out;

  const int Mq = B_ * NQ_;   // 20000
  const int Mv = B_ * S_;    // 39120
  const int BIG = 1 << 30;

  conv_weights<<<2944, 256, 0, stream>>>(Wv, Woff, Wa, Wo, W1, W2, wts);
  prep_inputs<<<(MV_P * 32 + MQ_P * 32) / 256, 256, 0, stream>>>(src, q_feat, q_pos, src_bf, q_bf);
  // value = src @ Wv + bv -> bf16 scatter [B][NH][S][DH]
  gemm_bf16<3><<<dim3(MV_P / 64, 2), 256, 0, stream>>>(src_bf, wts + 0, bv, bv, BIG, val_bf, MV_P, 256, 256, Mv);
  // [off | attn-logits] = q @ [Woff|Wa] + [boff|ba]  (bf16, N=384)
  gemm_bf16<4><<<dim3(MQ_P / 64, 3), 256, 0, stream>>>(q_bf, wts + 65536, boff, ba, 256, oa_bf, MQ_P, 384, 256, MQ_P);
  // deformable sampling (softmax fused) -> ms bf16
  msdeform_kernel<<<(Mq * 64) / 256, 256, 0, stream>>>(val_bf, oa_bf, q_ref, vr, ms_bf);
  // a = ms @ Wo + bo  (f32)
  gemm_bf16<0><<<dim3(MQ_P / 64, 2), 256, 0, stream>>>(ms_bf, wts + 163840, bo, bo, BIG, a_f, MQ_P, 256, 256, MQ_P);
  // x = LN(q_feat + a), plus bf16 copy
  add_ln_kernel<<<(Mq + 3) / 4, 256, 0, stream>>>(q_feat, a_f, g1, be1, x_f, x_bf, Mq);
  // h1 = relu(x @ W1 + bf1)  (bf16)
  gemm_bf16<2><<<dim3(MQ_P / 64, 8), 256, 0, stream>>>(x_bf, wts + 229376, bf1, bf1, BIG, h1_bf, MQ_P, 1024, 256, MQ_P);
  // f2 = h1 @ W2 + bf2  (f32)
  gemm_bf16<0><<<dim3(MQ_P / 64, 2), 256, 0, stream>>>(h1_bf, wts + 491520, bf2, bf2, BIG, f2_f, MQ_P, 256, 1024, MQ_P);
  // out = LN(x + f2)
  add_ln_kernel<<<(Mq + 3) / 4, 256, 0, stream>>>(x_f, f2_f, g2, be2, outp, nullptr, Mq);
}

// Round 6
// 213.336 us; speedup vs baseline: 1.6475x; 1.6475x over previous
//
#include <hip/hip_runtime.h>
#include <hip/hip_bf16.h>
#include <cstdint>

#define B_   2
#define NQ_  10000
#define C_   256
#define NH_  8
#define DH_  32
#define DFF_ 1024
#define S_   19560
#define MQ_P 20096   // 157*128
#define MV_P 39168   // 306*128

typedef __attribute__((ext_vector_type(8))) short short8;
typedef __attribute__((ext_vector_type(4))) float f32x4;

__device__ __forceinline__ void gload16(const void* g, void* l) {
  __builtin_amdgcn_global_load_lds(
      (const __attribute__((address_space(1))) unsigned int*)g,
      (__attribute__((address_space(3))) unsigned int*)l, 16, 0, 0);
}

__device__ __forceinline__ float bflo(unsigned u) {
  union { unsigned u; float f; } c; c.u = u << 16; return c.f;
}
__device__ __forceinline__ float bfhi(unsigned u) {
  union { unsigned u; float f; } c; c.u = u & 0xffff0000u; return c.f;
}

// ------------------------------------------------------------- weight conv+T
// Wt[n][k] = bf16(W[k][n]); layout: Wv | Woff | Wa | Wo | W1 | W2
__global__ __launch_bounds__(256) void conv_weights(
    const float* __restrict__ Wv, const float* __restrict__ Woff,
    const float* __restrict__ Wa, const float* __restrict__ Wo,
    const float* __restrict__ W1, const float* __restrict__ W2,
    __hip_bfloat16* __restrict__ wbase) {
  int idx = blockIdx.x * 256 + threadIdx.x;
  const float* W; __hip_bfloat16* Wt; int K, N, local;
  if (idx < 65536)        { W = Wv;   Wt = wbase + 0;      K = 256;  N = 256;  local = idx; }
  else if (idx < 131072)  { W = Woff; Wt = wbase + 65536;  K = 256;  N = 256;  local = idx - 65536; }
  else if (idx < 163840)  { W = Wa;   Wt = wbase + 131072; K = 256;  N = 128;  local = idx - 131072; }
  else if (idx < 229376)  { W = Wo;   Wt = wbase + 163840; K = 256;  N = 256;  local = idx - 163840; }
  else if (idx < 491520)  { W = W1;   Wt = wbase + 229376; K = 256;  N = 1024; local = idx - 229376; }
  else if (idx < 753664)  { W = W2;   Wt = wbase + 491520; K = 1024; N = 256;  local = idx - 491520; }
  else return;
  int k = local % K, n = local / K;
  Wt[(long)n * K + k] = __float2bfloat16(W[(long)k * N + n]);
}

// ------------------------------------------------------------- input prep
__global__ __launch_bounds__(256) void prep_inputs(
    const float* __restrict__ src, const float* __restrict__ qf,
    const float* __restrict__ qp, __hip_bfloat16* __restrict__ src_bf,
    __hip_bfloat16* __restrict__ q_bf) {
  long idx = (long)blockIdx.x * 256 + threadIdx.x;
  union { __hip_bfloat16 h[8]; uint4 u; } o;
  if (idx < (long)MV_P * 32) {
    int row = idx >> 5, c8 = (idx & 31) * 8;
    if (row < B_ * S_) {
      const float4 a = *reinterpret_cast<const float4*>(src + (long)row * 256 + c8);
      const float4 b = *reinterpret_cast<const float4*>(src + (long)row * 256 + c8 + 4);
      o.h[0] = __float2bfloat16(a.x); o.h[1] = __float2bfloat16(a.y);
      o.h[2] = __float2bfloat16(a.z); o.h[3] = __float2bfloat16(a.w);
      o.h[4] = __float2bfloat16(b.x); o.h[5] = __float2bfloat16(b.y);
      o.h[6] = __float2bfloat16(b.z); o.h[7] = __float2bfloat16(b.w);
    } else o.u = make_uint4(0, 0, 0, 0);
    *reinterpret_cast<uint4*>(src_bf + (long)row * 256 + c8) = o.u;
  } else {
    idx -= (long)MV_P * 32;
    int row = idx >> 5, c8 = (idx & 31) * 8;
    if (row < B_ * NQ_) {
      const float4 a0 = *reinterpret_cast<const float4*>(qf + (long)row * 256 + c8);
      const float4 a1 = *reinterpret_cast<const float4*>(qf + (long)row * 256 + c8 + 4);
      const float4 b0 = *reinterpret_cast<const float4*>(qp + (long)row * 256 + c8);
      const float4 b1 = *reinterpret_cast<const float4*>(qp + (long)row * 256 + c8 + 4);
      o.h[0] = __float2bfloat16(a0.x + b0.x); o.h[1] = __float2bfloat16(a0.y + b0.y);
      o.h[2] = __float2bfloat16(a0.z + b0.z); o.h[3] = __float2bfloat16(a0.w + b0.w);
      o.h[4] = __float2bfloat16(a1.x + b1.x); o.h[5] = __float2bfloat16(a1.y + b1.y);
      o.h[6] = __float2bfloat16(a1.z + b1.z); o.h[7] = __float2bfloat16(a1.w + b1.w);
    } else o.u = make_uint4(0, 0, 0, 0);
    *reinterpret_cast<uint4*>(q_bf + (long)row * 256 + c8) = o.u;
  }
}

// ------------------------------------------------------------- MFMA GEMM
template <int MODE>
__global__ __launch_bounds__(256) void gemm_bf16(
    const __hip_bfloat16* __restrict__ A, const __hip_bfloat16* __restrict__ Bt,
    const float* __restrict__ bias, const float* __restrict__ bias2, int bsplit,
    void* __restrict__ Cp, int M, int N, int K, int Mreal) {
  __shared__ short smA[64 * 64];    // 8KB
  __shared__ short smB[128 * 64];   // 16KB
  const int tid = threadIdx.x;
  const int lane = tid & 63;
  const int w = tid >> 6;
  const int wr = w >> 1, wc = w & 1;
  const long bm = (long)blockIdx.x * 64;
  const long bn = (long)blockIdx.y * 128;

  f32x4 acc[2][4];
#pragma unroll
  for (int i = 0; i < 2; ++i)
#pragma unroll
    for (int j = 0; j < 4; ++j) acc[i][j] = (f32x4)(0.f);

  const int srow = tid >> 3;                 // 0..31
  const int su = (tid & 7) ^ (srow & 7);     // pre-swizzled k-unit
  const __hip_bfloat16* Ag = A + (bm + srow) * (long)K + su * 8;
  const __hip_bfloat16* Bg = Bt + (bn + srow) * (long)K + su * 8;
  char* lA = (char*)smA + tid * 16;
  char* lB = (char*)smB + tid * 16;

  for (int k0 = 0; k0 < K; k0 += 64) {
    gload16(Ag,           lA);
    gload16(Ag + 32L * K, lA + 4096);
    gload16(Bg,           lB);
    gload16(Bg + 32L * K, lB + 4096);
    gload16(Bg + 64L * K, lB + 8192);
    gload16(Bg + 96L * K, lB + 12288);
    Ag += 64; Bg += 64;
    __syncthreads();
#pragma unroll
    for (int ks = 0; ks < 2; ++ks) {
      const int u = ks * 4 + (lane >> 4);
      short8 af[2], bf[4];
#pragma unroll
      for (int mi = 0; mi < 2; ++mi) {
        const int r = wr * 32 + (lane & 15) + mi * 16;
        af[mi] = *reinterpret_cast<const short8*>(
            (char*)smA + r * 128 + ((u ^ (r & 7)) * 16));
      }
#pragma unroll
      for (int ni = 0; ni < 4; ++ni) {
        const int r = wc * 64 + (lane & 15) + ni * 16;
        bf[ni] = *reinterpret_cast<const short8*>(
            (char*)smB + r * 128 + ((u ^ (r & 7)) * 16));
      }
#pragma unroll
      for (int mi = 0; mi < 2; ++mi)
#pragma unroll
        for (int ni = 0; ni < 4; ++ni)
          acc[mi][ni] = __builtin_amdgcn_mfma_f32_16x16x32_bf16(af[mi], bf[ni], acc[mi][ni], 0, 0, 0);
    }
    __syncthreads();
  }

  const int crow0 = wr * 32 + ((lane >> 4) << 2);
  const int ccol0 = wc * 64 + (lane & 15);
#pragma unroll
  for (int mi = 0; mi < 2; ++mi) {
#pragma unroll
    for (int ni = 0; ni < 4; ++ni) {
      const int col = bn + ccol0 + ni * 16;
      const float bs = (col < bsplit) ? bias[col] : bias2[col - bsplit];
#pragma unroll
      for (int r = 0; r < 4; ++r) {
        const long row = bm + crow0 + mi * 16 + r;
        float v = acc[mi][ni][r] + bs;
        if (MODE == 0) {
          ((float*)Cp)[row * N + col] = v;
        } else if (MODE == 2) {
          ((__hip_bfloat16*)Cp)[row * N + col] = __float2bfloat16(fmaxf(v, 0.f));
        } else if (MODE == 4) {
          ((__hip_bfloat16*)Cp)[row * N + col] = __float2bfloat16(v);
        } else { // MODE 3
          if (row < Mreal) {
            const int b = (row >= S_) ? 1 : 0;
            const long s = row - (long)b * S_;
            const int h = col >> 5, dh = col & 31;
            ((__hip_bfloat16*)Cp)[(((long)(b * 8 + h)) * S_ + s) * 32 + dh] = __float2bfloat16(v);
          }
        }
      }
    }
  }
}

// ------------------------------------------------------------- ms_deform
// value bf16 [B][NH][S][32]; oa bf16 [bq][384]: 0..255 offsets (h,l,p,2),
// 256..383 logits (h,l*p). out bf16 [MQ_P][256] rows<20000.
// 128 threads (2 waves) per query: tid7 = h(3b) | l(2b) | dq(2b).
// Each lane: 8 channels, one level, 4 points. acc[8], one uint4 per corner.
// Softmax and acc reduced over l-lanes via shfl_xor(8,16) (in-wave; dq's
// high bit is the wave bit and dq needs no reduction).
__global__ __launch_bounds__(256) void msdeform_kernel(
    const __hip_bfloat16* __restrict__ value, const __hip_bfloat16* __restrict__ oa,
    const float* __restrict__ q_ref, const float* __restrict__ vr,
    __hip_bfloat16* __restrict__ out) {
  const int t = blockIdx.x * 256 + threadIdx.x;
  const int tid7 = t & 127;
  const int h = tid7 & 7;
  const int l = (tid7 >> 3) & 3;
  const int dq = tid7 >> 5;                                 // 0..3
  const int bq = __builtin_amdgcn_readfirstlane(t >> 7);    // wave-uniform
  const int b = (bq >= NQ_) ? 1 : 0;

  const int W  = (l == 0) ? 160 : (l == 1) ? 80 : (l == 2) ? 40 : 20;
  const int H  = (l == 0) ? 92  : (l == 1) ? 46 : (l == 2) ? 23 : 12;
  const int S0 = (l == 0) ? 0 : (l == 1) ? 14720 : (l == 2) ? 18400 : 19320;

  const __hip_bfloat16* oabase = oa + (long)bq * 384;       // SGPR base
  // distributed softmax: each lane owns its 4 logits; reduce across l-lanes
  const uint2 mu = *reinterpret_cast<const uint2*>(oabase + 256 + h * 16 + l * 4);
  const float l0 = bflo(mu.x), l1 = bfhi(mu.x), l2 = bflo(mu.y), l3 = bfhi(mu.y);
  float mx = fmaxf(fmaxf(l0, l1), fmaxf(l2, l3));
  mx = fmaxf(mx, __shfl_xor(mx, 8, 64));
  mx = fmaxf(mx, __shfl_xor(mx, 16, 64));
  const float e0 = __expf(l0 - mx), e1 = __expf(l1 - mx);
  const float e2 = __expf(l2 - mx), e3 = __expf(l3 - mx);
  float sum = e0 + e1 + e2 + e3;
  sum += __shfl_xor(sum, 8, 64);
  sum += __shfl_xor(sum, 16, 64);
  const float inv = 1.f / sum;
  const float w0 = e0 * inv, w1 = e1 * inv, w2 = e2 * inv, w3 = e3 * inv;

  const uint4 ou = *reinterpret_cast<const uint4*>(oabase + h * 32 + l * 8);

  const float rx = q_ref[(long)bq * 2 + 0];                 // scalar loads
  const float ry = q_ref[(long)bq * 2 + 1];
  const float2 vv = *reinterpret_cast<const float2*>(vr + (b * 4 + l) * 2);
  const float refxW = rx * vv.x * W - 0.5f;
  const float refyH = ry * vv.y * H - 0.5f;
  const __hip_bfloat16* vb = value + ((long)(b * 8 + h) * S_ + S0) * 32 + dq * 8;

  float acc[8] = {};
#define SAMPLE(OX, OY, AW)                                                     \
  {                                                                            \
    const float x = refxW + (OX);                                              \
    const float y = refyH + (OY);                                              \
    const float x0f = floorf(x), y0f = floorf(y);                              \
    const float lx = x - x0f, ly = y - y0f;                                    \
    const int x0 = (int)x0f, y0 = (int)y0f;                                    \
    const int x1 = x0 + 1, y1 = y0 + 1;                                        \
    const float wx0 = ((unsigned)x0 < (unsigned)W) ? (1.f - lx) : 0.f;         \
    const float wx1 = ((unsigned)x1 < (unsigned)W) ? lx : 0.f;                 \
    const float wy0 = ((unsigned)y0 < (unsigned)H) ? (1.f - ly) : 0.f;         \
    const float wy1 = ((unsigned)y1 < (unsigned)H) ? ly : 0.f;                 \
    const int x0c = min(max(x0, 0), W - 1);                                    \
    const int x1c = min(max(x1, 0), W - 1);                                    \
    const int y0c = min(max(y0, 0), H - 1);                                    \
    const int y1c = min(max(y1, 0), H - 1);                                    \
    const float w00 = (AW) * wx0 * wy0, w10 = (AW) * wx1 * wy0;                \
    const float w01 = (AW) * wx0 * wy1, w11 = (AW) * wx1 * wy1;                \
    const uint4 ca = *reinterpret_cast<const uint4*>(vb + (long)(y0c * W + x0c) * 32); \
    const uint4 cb = *reinterpret_cast<const uint4*>(vb + (long)(y0c * W + x1c) * 32); \
    const uint4 cc = *reinterpret_cast<const uint4*>(vb + (long)(y1c * W + x0c) * 32); \
    const uint4 cd = *reinterpret_cast<const uint4*>(vb + (long)(y1c * W + x1c) * 32); \
    acc[0] += w00 * bflo(ca.x) + w10 * bflo(cb.x) + w01 * bflo(cc.x) + w11 * bflo(cd.x); \
    acc[1] += w00 * bfhi(ca.x) + w10 * bfhi(cb.x) + w01 * bfhi(cc.x) + w11 * bfhi(cd.x); \
    acc[2] += w00 * bflo(ca.y) + w10 * bflo(cb.y) + w01 * bflo(cc.y) + w11 * bflo(cd.y); \
    acc[3] += w00 * bfhi(ca.y) + w10 * bfhi(cb.y) + w01 * bfhi(cc.y) + w11 * bfhi(cd.y); \
    acc[4] += w00 * bflo(ca.z) + w10 * bflo(cb.z) + w01 * bflo(cc.z) + w11 * bflo(cd.z); \
    acc[5] += w00 * bfhi(ca.z) + w10 * bfhi(cb.z) + w01 * bfhi(cc.z) + w11 * bfhi(cd.z); \
    acc[6] += w00 * bflo(ca.w) + w10 * bflo(cb.w) + w01 * bflo(cc.w) + w11 * bflo(cd.w); \
    acc[7] += w00 * bfhi(ca.w) + w10 * bfhi(cb.w) + w01 * bfhi(cc.w) + w11 * bfhi(cd.w); \
  }
  SAMPLE(bflo(ou.x), bfhi(ou.x), w0)
  SAMPLE(bflo(ou.y), bfhi(ou.y), w1)
  SAMPLE(bflo(ou.z), bfhi(ou.z), w2)
  SAMPLE(bflo(ou.w), bfhi(ou.w), w3)
#undef SAMPLE

#pragma unroll
  for (int j = 0; j < 8; ++j) acc[j] += __shfl_xor(acc[j], 8, 64);
#pragma unroll
  for (int j = 0; j < 8; ++j) acc[j] += __shfl_xor(acc[j], 16, 64);

  if (l == 0) {
    union { __hip_bfloat16 hh[8]; uint4 u; } o0;
#pragma unroll
    for (int j = 0; j < 8; ++j) o0.hh[j] = __float2bfloat16(acc[j]);
    *reinterpret_cast<uint4*>(out + (long)bq * 256 + h * 32 + dq * 8) = o0.u;
  }
}

// ------------------------------------------------------------- residual+LN
__global__ __launch_bounds__(256) void add_ln_kernel(
    const float* __restrict__ res, const float* __restrict__ xin,
    const float* __restrict__ gamma, const float* __restrict__ beta,
    float* __restrict__ out, __hip_bfloat16* __restrict__ out_bf, int nrows) {
  int row = blockIdx.x * 4 + (threadIdx.x >> 6);
  int lane = threadIdx.x & 63;
  if (row >= nrows) return;
  const float4 r4 = *reinterpret_cast<const float4*>(res + (long)row * 256 + lane * 4);
  const float4 x4 = *reinterpret_cast<const float4*>(xin + (long)row * 256 + lane * 4);
  float tv[4] = {r4.x + x4.x, r4.y + x4.y, r4.z + x4.z, r4.w + x4.w};
  float s = tv[0] + tv[1] + tv[2] + tv[3];
#pragma unroll
  for (int o = 32; o > 0; o >>= 1) s += __shfl_xor(s, o, 64);
  float mean = s * (1.f / 256.f);
  float vs = 0.f;
#pragma unroll
  for (int j = 0; j < 4; ++j) { float dd = tv[j] - mean; vs += dd * dd; }
#pragma unroll
  for (int o = 32; o > 0; o >>= 1) vs += __shfl_xor(vs, o, 64);
  float inv = rsqrtf(vs * (1.f / 256.f) + 1e-5f);
  const float4 g = *reinterpret_cast<const float4*>(gamma + lane * 4);
  const float4 be = *reinterpret_cast<const float4*>(beta + lane * 4);
  float4 o4;
  o4.x = (tv[0] - mean) * inv * g.x + be.x;
  o4.y = (tv[1] - mean) * inv * g.y + be.y;
  o4.z = (tv[2] - mean) * inv * g.z + be.z;
  o4.w = (tv[3] - mean) * inv * g.w + be.w;
  *reinterpret_cast<float4*>(out + (long)row * 256 + lane * 4) = o4;
  if (out_bf) {
    union { __hip_bfloat16 h[4]; uint2 u; } p;
    p.h[0] = __float2bfloat16(o4.x); p.h[1] = __float2bfloat16(o4.y);
    p.h[2] = __float2bfloat16(o4.z); p.h[3] = __float2bfloat16(o4.w);
    *reinterpret_cast<uint2*>(out_bf + (long)row * 256 + lane * 4) = p.u;
  }
}

// ------------------------------------------------------------- launch
extern "C" void kernel_launch(void* const* d_in, const int* in_sizes, int n_in,
                              void* d_out, int out_size, void* d_ws, size_t ws_size,
                              hipStream_t stream) {
  const float* src    = (const float*)d_in[0];
  const float* q_feat = (const float*)d_in[1];
  const float* q_pos  = (const float*)d_in[2];
  const float* q_ref  = (const float*)d_in[3];
  const float* vr     = (const float*)d_in[4];
  const float* Wv     = (const float*)d_in[5];
  const float* bv     = (const float*)d_in[6];
  const float* Woff   = (const float*)d_in[7];
  const float* boff   = (const float*)d_in[8];
  const float* Wa     = (const float*)d_in[9];
  const float* ba     = (const float*)d_in[10];
  const float* Wo     = (const float*)d_in[11];
  const float* bo     = (const float*)d_in[12];
  const float* g1     = (const float*)d_in[13];
  const float* be1    = (const float*)d_in[14];
  const float* W1     = (const float*)d_in[15];
  const float* bf1    = (const float*)d_in[16];
  const float* W2     = (const float*)d_in[17];
  const float* bf2    = (const float*)d_in[18];
  const float* g2     = (const float*)d_in[19];
  const float* be2    = (const float*)d_in[20];

  char* ws = (char*)d_ws;
  __hip_bfloat16* src_bf = (__hip_bfloat16*)(ws + 0);          // 20,054,016
  float*          a_f    = (float*)(ws + 0);                   // reuse (20,578,304)
  __hip_bfloat16* q_bf   = (__hip_bfloat16*)(ws + 20578304);   // 10,289,152
  __hip_bfloat16* val_bf = (__hip_bfloat16*)(ws + 30867456);   // 20,029,440
  __hip_bfloat16* oa_bf  = (__hip_bfloat16*)(ws + 50896896);   // 15,433,728
  __hip_bfloat16* h1_bf  = (__hip_bfloat16*)(ws + 20578304);   // reuse q/val/oa
  __hip_bfloat16* ms_bf  = (__hip_bfloat16*)(ws + 81764352);   // 10,289,152
  float*          f2_f   = (float*)(ws + 71475200);            // dead region reuse
  float*          x_f    = (float*)(ws + 92053504);            // 20,578,304
  __hip_bfloat16* x_bf   = (__hip_bfloat16*)(ws + 112631808);  // 10,289,152
  __hip_bfloat16* wts    = (__hip_bfloat16*)(ws + 122920960);  // 1,507,328
  float* outp = (float*)d_out;

  const int Mq = B_ * NQ_;   // 20000
  const int Mv = B_ * S_;    // 39120
  const int BIG = 1 << 30;

  conv_weights<<<2944, 256, 0, stream>>>(Wv, Woff, Wa, Wo, W1, W2, wts);
  prep_inputs<<<(MV_P * 32 + MQ_P * 32) / 256, 256, 0, stream>>>(src, q_feat, q_pos, src_bf, q_bf);
  // value = src @ Wv + bv -> bf16 scatter [B][NH][S][DH]
  gemm_bf16<3><<<dim3(MV_P / 64, 2), 256, 0, stream>>>(src_bf, wts + 0, bv, bv, BIG, val_bf, MV_P, 256, 256, Mv);
  // [off | attn-logits] = q @ [Woff|Wa] + [boff|ba]  (bf16, N=384)
  gemm_bf16<4><<<dim3(MQ_P / 64, 3), 256, 0, stream>>>(q_bf, wts + 65536, boff, ba, 256, oa_bf, MQ_P, 384, 256, MQ_P);
  // deformable sampling (softmax fused) -> ms bf16; 128 threads/query
  msdeform_kernel<<<(Mq * 128) / 256, 256, 0, stream>>>(val_bf, oa_bf, q_ref, vr, ms_bf);
  // a = ms @ Wo + bo  (f32)
  gemm_bf16<0><<<dim3(MQ_P / 64, 2), 256, 0, stream>>>(ms_bf, wts + 163840, bo, bo, BIG, a_f, MQ_P, 256, 256, MQ_P);
  // x = LN(q_feat + a), plus bf16 copy
  add_ln_kernel<<<(Mq + 3) / 4, 256, 0, stream>>>(q_feat, a_f, g1, be1, x_f, x_bf, Mq);
  // h1 = relu(x @ W1 + bf1)  (bf16)
  gemm_bf16<2><<<dim3(MQ_P / 64, 8), 256, 0, stream>>>(x_bf, wts + 229376, bf1, bf1, BIG, h1_bf, MQ_P, 1024, 256, MQ_P);
  // f2 = h1 @ W2 + bf2  (f32)
  gemm_bf16<0><<<dim3(MQ_P / 64, 2), 256, 0, stream>>>(h1_bf, wts + 491520, bf2, bf2, BIG, f2_f, MQ_P, 256, 1024, MQ_P);
  // out = LN(x + f2)
  add_ln_kernel<<<(Mq + 3) / 4, 256, 0, stream>>>(x_f, f2_f, g2, be2, outp, nullptr, Mq);
}